// Round 13
// baseline (435.178 us; speedup 1.0000x reference)
//
#include <hip/hip_runtime.h>

#define B_ 16
#define S_ 12
#define N_ 325
#define E_ 2600
#define CIN_ 32
#define H_ 64
#define HEADS_ 4
#define COUT_ 12
#define BS_ (B_*S_)          // 192
#define ROWS_ (BS_*N_)       // 62400
#define EN_ (E_+N_)          // 2925
#define QK_ 256
#define HB_ (B_/2)           // 8 b per half
#define HBS_ (BS_/2)         // 96
#define HROWS_ (ROWS_/2)     // 31200

__device__ __forceinline__ int swz8(int bid, int cpx) {
  return (bid & 7) * cpx + (bid >> 3);   // grid must be multiple of 8
}

// ---------------- degree / norm / CSR pointers ----------------
__global__ void k_deg(const int* __restrict__ ei, int* __restrict__ ptr_gcn,
                      int* __restrict__ ptr_att, float* __restrict__ dinv) {
  __shared__ int cnt[N_];
  for (int i = threadIdx.x; i < N_; i += blockDim.x) cnt[i] = 0;
  __syncthreads();
  for (int e = threadIdx.x; e < E_; e += blockDim.x)
    atomicAdd(&cnt[ei[E_ + e]], 1);   // col = target
  __syncthreads();
  for (int n = threadIdx.x; n < N_; n += blockDim.x)
    dinv[n] = rsqrtf((float)(cnt[n] + 1));
  if (threadIdx.x == 0) {
    int a = 0, g = 0;
    for (int n = 0; n < N_; n++) {
      ptr_att[n] = a; ptr_gcn[n] = g;
      a += cnt[n]; g += cnt[n] + 1;   // gcn bucket has +1 self-loop slot
    }
    ptr_att[N_] = a; ptr_gcn[N_] = g;
  }
}

// ---------------- deterministic CSR fill (stable rank) ----------------
__global__ void k_fill(const int* __restrict__ ei, const int* __restrict__ ptr_gcn,
                       const int* __restrict__ ptr_att, const float* __restrict__ dinv,
                       int* __restrict__ gcn_src, float* __restrict__ gcn_w,
                       int* __restrict__ att_src) {
  __shared__ int cols[E_];
  for (int i = threadIdx.x; i < E_; i += blockDim.x) cols[i] = ei[E_ + i];
  __syncthreads();
  int e = blockIdx.x * blockDim.x + threadIdx.x;
  if (e >= EN_) return;
  int t = (e < E_) ? cols[e] : (e - E_);
  int s = (e < E_) ? ei[e]   : (e - E_);
  int lim = (e < E_) ? e : E_;
  int rank = 0;
  for (int j = 0; j < lim; j++) rank += (cols[j] == t);
  int pos = ptr_gcn[t] + rank;
  gcn_src[pos] = s;
  gcn_w[pos] = dinv[s] * dinv[t];
  if (e < E_) att_src[ptr_att[t] + rank] = s;
}

// ---------------- setup: AB, cd, Wkt (=G_h^T packed), vvec, c4, zero256 ----------------
// blocks 0..239: AB ; 240: cd ; 241..304: Wkt ; 305: vvec + c4 + zero256
__global__ void k_abcd(const float* __restrict__ Wv, const float* __restrict__ Wsm,
                       const float* __restrict__ Wl, const float* __restrict__ bl,
                       const float* __restrict__ bsv, const float* __restrict__ bvv,
                       const float* __restrict__ Wq, const float* __restrict__ bq,
                       const float* __restrict__ Wk, const float* __restrict__ bk,
                       float* __restrict__ AB, float* __restrict__ cd,
                       float* __restrict__ Wkt, float* __restrict__ vc,
                       float* __restrict__ zero256) {
  int t = threadIdx.x;
  if (blockIdx.x < 240) {
    int s = blockIdx.x / 20, dblk = blockIdx.x % 20;
    int dl = t >> 4, co = t & 15;
    int d = dblk * 16 + dl;             // 0..319
    float acc = 0.f;
    if (co < 12) {
      if (d < 256) {
        int h = d >> 6, dd = d & 63;
        for (int j = 0; j < 64; j++)
          acc += Wv[dd * 256 + h * 64 + j] * Wl[(size_t)(s * 256 + h * 64 + j) * 12 + co];
      } else {
        int d0 = d - 256;
        for (int J = 0; J < 256; J++)
          acc += Wsm[d0 * 256 + J] * Wl[(size_t)(s * 256 + J) * 12 + co];
      }
    }
    AB[((size_t)s * 320 + d) * 16 + co] = acc;
  } else if (blockIdx.x == 240) {
    __shared__ float red[2][16][17];
    int co = t & 15, chunk = t >> 4;
    float c = 0.f, dv = 0.f;
    if (co < 12) {
      for (int J = chunk * 192; J < chunk * 192 + 192; J++) {
        float wl = Wl[(size_t)J * 12 + co];
        c  += bsv[J & 255] * wl;
        dv += bvv[J & 255] * wl;
      }
    }
    red[0][chunk][co] = c;
    red[1][chunk][co] = dv;
    __syncthreads();
    if (t < 16) {
      float s0 = 0.f;
      for (int ch = 0; ch < 16; ch++) s0 += red[0][ch][t];
      cd[t] = s0 + ((t < 12) ? bl[t] : 0.f);
    } else if (t < 32) {
      int co2 = t - 16;
      float s1 = 0.f;
      for (int ch = 0; ch < 16; ch++) s1 += red[1][ch][co2];
      cd[16 + co2] = s1;
    }
  } else if (blockIdx.x < 305) {
    // Wkt[e][h*64+d] = G_h[d][e] = sum_i Wq[d][h*64+i] * Wk[e][h*64+i]
    int idx = (blockIdx.x - 241) * 256 + t;    // 0..16383
    int e = idx >> 8, col = idx & 255;
    int h = col >> 6, d = col & 63;
    float acc = 0.f;
    const float* wqr = Wq + (size_t)d * QK_ + h * 64;
    const float* wkr = Wk + (size_t)e * QK_ + h * 64;
#pragma unroll 8
    for (int i = 0; i < 64; i++) acc += wqr[i] * wkr[i];
    Wkt[(size_t)e * QK_ + col] = acc;
  } else {
    // vvec[h*64+e] = sum_i Wk[e][h*64+i] * bq[h*64+i] ; vc[256..259] = c_h ; zero256
    int h = t >> 6, e = t & 63;
    float acc = 0.f;
    const float* wkr = Wk + (size_t)e * QK_ + h * 64;
    const float* bqr = bq + h * 64;
#pragma unroll 8
    for (int i = 0; i < 64; i++) acc += wkr[i] * bqr[i];
    vc[t] = acc;
    if (t < 4) {
      float cc = 0.f;
      for (int i = 0; i < 64; i++) cc += bq[t * 64 + i] * bk[t * 64 + i];
      vc[256 + t] = cc;
    }
    zero256[t] = 0.f;
  }
}

// ---------------- GCN aggregation (SpMM), 4-way unrolled independent gathers ----------------
template<int K>
__global__ __launch_bounds__(256) void k_agg(const float* __restrict__ hin,
    const int* __restrict__ ptr, const int* __restrict__ src,
    const float* __restrict__ wgt, float* __restrict__ ag) {
  int wid = threadIdx.x >> 6, lane = threadIdx.x & 63;
  int n = blockIdx.x * 4 + wid;
  int bs = blockIdx.y;
  if (n >= N_ || (K != 64 && lane >= K)) return;
  int p0 = ptr[n], p1 = ptr[n + 1];
  const float* base = hin + (size_t)bs * N_ * K;
  float a0 = 0.f, a1 = 0.f, a2 = 0.f, a3 = 0.f;
  int e = p0;
  for (; e + 4 <= p1; e += 4) {
    a0 += wgt[e]     * base[src[e]     * K + lane];
    a1 += wgt[e + 1] * base[src[e + 1] * K + lane];
    a2 += wgt[e + 2] * base[src[e + 2] * K + lane];
    a3 += wgt[e + 3] * base[src[e + 3] * K + lane];
  }
  for (; e < p1; ++e) a0 += wgt[e] * base[src[e] * K + lane];
  ag[((size_t)bs * N_ + n) * K + lane] = (a0 + a1) + (a2 + a3);
}

// ---------------- tiled GEMM: C[M x 64-slice] = A[M x K] @ W[:,c0:c0+64] + bias (opt relu) ----
template<int K, bool RELU>
__global__ __launch_bounds__(256) void k_gemm(
    const float* __restrict__ A, int M,
    const float* __restrict__ W0, const float* __restrict__ b0, float* __restrict__ C0,
    const float* __restrict__ W1, const float* __restrict__ b1, float* __restrict__ C1,
    int wstride, int cstride, int nct) {
  __shared__ float Ast[K][136];
  __shared__ float Wsh[K][68];
  int t = threadIdx.x;
  int ct = blockIdx.y;
  const float* W   = (ct < nct) ? W0 : W1;
  const float* bia = (ct < nct) ? b0 : b1;
  float* C         = (ct < nct) ? C0 : C1;
  int c0 = (ct & (nct - 1)) * 64;          // nct is 1 or 4 (power of 2)
  for (int i = t; i < K * 64; i += 256)
    Wsh[i >> 6][i & 63] = W[(size_t)(i >> 6) * wstride + c0 + (i & 63)];
  int r0 = blockIdx.x * 128;
  constexpr int KQ = K / 4;
#pragma unroll
  for (int it = 0; it < KQ / 2; ++it) {    // 128*KQ/256 iters
    int idx = it * 256 + t;
    int dq = idx >> 7, rl = idx & 127;
    int ar = min(r0 + rl, M - 1);
    float4 v = *(const float4*)(A + (size_t)ar * K + dq * 4);
    Ast[dq * 4 + 0][rl] = v.x; Ast[dq * 4 + 1][rl] = v.y;
    Ast[dq * 4 + 2][rl] = v.z; Ast[dq * 4 + 3][rl] = v.w;
  }
  __syncthreads();
  int tr = t >> 4, tc = t & 15;            // rows tr*8..+7, cols tc*4..+3
  float acc[8][4];
#pragma unroll
  for (int i = 0; i < 8; i++)
#pragma unroll
    for (int j = 0; j < 4; j++) acc[i][j] = 0.f;
#pragma unroll 8
  for (int k = 0; k < K; k++) {
    float4 w4 = *(const float4*)&Wsh[k][tc * 4];
    float4 a0 = *(const float4*)&Ast[k][tr * 8];
    float4 a1 = *(const float4*)&Ast[k][tr * 8 + 4];
    const float av[8] = {a0.x, a0.y, a0.z, a0.w, a1.x, a1.y, a1.z, a1.w};
#pragma unroll
    for (int i = 0; i < 8; i++) {
      acc[i][0] += av[i] * w4.x; acc[i][1] += av[i] * w4.y;
      acc[i][2] += av[i] * w4.z; acc[i][3] += av[i] * w4.w;
    }
  }
  float4 b4 = *(const float4*)&bia[c0 + tc * 4];
#pragma unroll
  for (int i = 0; i < 8; i++) {
    int row = r0 + tr * 8 + i;
    if (row < M) {
      float4 o = make_float4(acc[i][0] + b4.x, acc[i][1] + b4.y,
                             acc[i][2] + b4.z, acc[i][3] + b4.w);
      if (RELU) {
        o.x = fmaxf(o.x, 0.f); o.y = fmaxf(o.y, 0.f);
        o.z = fmaxf(o.z, 0.f); o.w = fmaxf(o.w, 0.f);
      }
      *(float4*)(C + (size_t)row * cstride + c0 + tc * 4) = o;
    }
  }
}

// ---------------- beta: bb[row][h] = xt_row . vvec_h + c_h ----------------
__global__ __launch_bounds__(256) void k_beta(const float* __restrict__ xt,
    const float* __restrict__ vc, float* __restrict__ bb) {
  __shared__ float vs[260];
  int t = threadIdx.x;
  vs[t] = vc[t];
  if (t < 4) vs[256 + t] = vc[256 + t];
  __syncthreads();
  int row = blockIdx.x * 64 + (t >> 2), h = t & 3;
  const float4* xr = (const float4*)(xt + (size_t)row * 64);
  const float4* vr = (const float4*)&vs[h * 64];
  float d0 = 0.f, d1 = 0.f;
#pragma unroll
  for (int j = 0; j < 16; j += 2) {
    float4 xa = xr[j], va = vr[j];
    float4 xb2 = xr[j + 1], vb = vr[j + 1];
    d0 += xa.x * va.x + xa.y * va.y + xa.z * va.z + xa.w * va.w;
    d1 += xb2.x * vb.x + xb2.y * vb.y + xb2.z * vb.z + xb2.w * vb.w;
  }
  bb[(size_t)row * 4 + h] = d0 + d1 + vs[256 + h];
}

// ---------------- fused attention + final-slice GEMM ----------------
// grid (82, 96): blockIdx.y = local bs (s = bs%12 uniform per block), x covers n in 4s.
// After online-softmax PV, each wave holds z (lane=dim, zn[4]) and xt row in LDS;
// partial[row][co] = sum_d z[d] AB[s][d][co] + sum_d xt[d] AB[s][256+d][co].
__global__ __launch_bounds__(256) void k_attnfin(const float* __restrict__ kt,
    const float* __restrict__ xt, const float* __restrict__ bb,
    const float* __restrict__ AB, const int* __restrict__ ptr,
    const int* __restrict__ src, int half, float* __restrict__ partial) {
  __shared__ float xs[4][68];
  __shared__ float ABs[320][17];           // pad 17: fin reads land 2 lanes/bank
  int t = threadIdx.x, wid = t >> 6, lane = t & 63;
  int bsl = blockIdx.y;                    // 0..95
  int s = bsl % 12;
  const float* ABg = AB + (size_t)s * 320 * 16;
  for (int i = t; i < 1280; i += 256) {    // stage AB slice (20 KB)
    float4 v = ((const float4*)ABg)[i];
    int d = i >> 2, q = (i & 3) * 4;
    ABs[d][q] = v.x; ABs[d][q + 1] = v.y; ABs[d][q + 2] = v.z; ABs[d][q + 3] = v.w;
  }
  int n = blockIdx.x * 4 + wid;
  const float* xb = xt + ((size_t)half * HBS_ + bsl) * N_ * 64;
  if (n < N_) xs[wid][lane] = xb[(size_t)n * 64 + lane];
  __syncthreads();
  if (n >= N_) return;                     // wave-uniform, after the only barrier
  int p0 = ptr[n], p1 = ptr[n + 1];
  int h = lane & 3, el = lane >> 2;
  const float* kb = kt + (size_t)bsl * N_ * QK_;
  const float* bbb = bb + ((size_t)half * HROWS_ + (size_t)bsl * N_) * 4;
  const float4* x4 = reinterpret_cast<const float4*>(&xs[wid][0]);
  float m = -INFINITY, den = 0.f;
  float zacc[4] = {0.f, 0.f, 0.f, 0.f};
  for (int base = p0; base < p1; base += 16) {
    int slot = base + el;
    bool valid = slot < p1;
    int sidx = valid ? src[slot] : 0;
    float logit = -INFINITY;
    if (valid) {
      const float4* k4 = reinterpret_cast<const float4*>(kb + (size_t)sidx * QK_ + h * 64);
      float d0 = 0.f, d1 = 0.f;
#pragma unroll
      for (int j = 0; j < 16; j += 2) {
        float4 ka = k4[j], kb2 = k4[j + 1];
        float4 xa = x4[j], xb2 = x4[j + 1];
        d0 += xa.x * ka.x + xa.y * ka.y + xa.z * ka.z + xa.w * ka.w;
        d1 += xb2.x * kb2.x + xb2.y * kb2.y + xb2.z * kb2.z + xb2.w * kb2.w;
      }
      logit = (d0 + d1 + bbb[sidx * 4 + h]) * 0.125f;   // 1/sqrt(64)
    }
    float cm = logit;
#pragma unroll
    for (int o = 4; o < 64; o <<= 1) cm = fmaxf(cm, __shfl_xor(cm, o));
    float mnew = fmaxf(m, cm);
    float scale = __expf(m - mnew);        // first chunk: exp(-inf)=0
    float w = valid ? __expf(logit - mnew) : 0.f;
    float wsum = w;
#pragma unroll
    for (int o = 4; o < 64; o <<= 1) wsum += __shfl_xor(wsum, o);
    den = den * scale + wsum;
#pragma unroll
    for (int h2 = 0; h2 < 4; h2++) zacc[h2] *= __shfl(scale, h2);
    int cnt = min(16, p1 - base);
    for (int e2 = 0; e2 < cnt; e2++) {
      int s_e = __shfl(sidx, e2 * 4);
      float xv = xb[(size_t)s_e * 64 + lane];
#pragma unroll
      for (int h2 = 0; h2 < 4; h2++)
        zacc[h2] += __shfl(w, e2 * 4 + h2) * xv;
    }
    m = mnew;
  }
  bool ok = p1 > p0;
  float zn[4];
#pragma unroll
  for (int h2 = 0; h2 < 4; h2++) {
    float dh = __shfl(den, h2);
    zn[h2] = ok ? zacc[h2] / (dh + 1e-16f) : 0.f;
  }
  // fused final-slice: per-lane contributions, butterfly reduce, lane0 writes 12
  float xv = xs[wid][lane];
  float pl[12];
#pragma unroll
  for (int co = 0; co < 12; co++)
    pl[co] = zn[0] * ABs[lane][co] + zn[1] * ABs[64 + lane][co]
           + zn[2] * ABs[128 + lane][co] + zn[3] * ABs[192 + lane][co]
           + xv * ABs[256 + lane][co];
#pragma unroll
  for (int o = 1; o < 64; o <<= 1) {
#pragma unroll
    for (int co = 0; co < 12; co++) pl[co] += __shfl_xor(pl[co], o);
  }
  if (lane == 0) {
    float* pr = partial + ((size_t)half * HROWS_ + (size_t)bsl * N_ + n) * 12;
    *(float4*)(pr)     = make_float4(pl[0], pl[1], pl[2], pl[3]);
    *(float4*)(pr + 4) = make_float4(pl[4], pl[5], pl[6], pl[7]);
    *(float4*)(pr + 8) = make_float4(pl[8], pl[9], pl[10], pl[11]);
  }
}

// ---------------- y = sum_s partial + cvec + 1{deg>0} dvec ----------------
__global__ void k_red(const float* __restrict__ partial, const float* __restrict__ cd,
                      const int* __restrict__ ptr, float* __restrict__ y) {
  int tg = blockIdx.x * 256 + threadIdx.x;
  if (tg >= B_ * N_ * 12) return;
  int bn = tg / 12, co = tg % 12;
  int b = bn / N_, n = bn % N_;
  float acc = cd[co];
  if (ptr[n + 1] > ptr[n]) acc += cd[16 + co];
  for (int s = 0; s < 12; s++)
    acc += partial[(((size_t)(b * 12 + s)) * N_ + n) * 12 + co];
  y[(size_t)bn * 12 + co] = acc;
}

extern "C" void kernel_launch(void* const* d_in, const int* in_sizes, int n_in,
                              void* d_out, int out_size, void* d_ws, size_t ws_size,
                              hipStream_t stream) {
  const float* x   = (const float*)d_in[0];
  const int*   ei  = (const int*)d_in[1];
  const float* Wg[4] = {(const float*)d_in[2], (const float*)d_in[4],
                        (const float*)d_in[6], (const float*)d_in[8]};
  const float* bg[4] = {(const float*)d_in[3], (const float*)d_in[5],
                        (const float*)d_in[7], (const float*)d_in[9]};
  const float* Wq = (const float*)d_in[10]; const float* bq = (const float*)d_in[11];
  const float* Wk = (const float*)d_in[12]; const float* bk = (const float*)d_in[13];
  const float* Wv = (const float*)d_in[14]; const float* bv = (const float*)d_in[15];
  const float* Ws = (const float*)d_in[16]; const float* bs = (const float*)d_in[17];
  const float* Wl = (const float*)d_in[18]; const float* bl = (const float*)d_in[19];
  float* y = (float*)d_out;

  char* p = (char*)d_ws;
  auto alloc = [&](size_t bytes) {
    char* r = p;
    p += (bytes + 255) & ~(size_t)255;
    return r;
  };
  float* dinv    = (float*)alloc(N_ * 4);
  int*   ptr_gcn = (int*)alloc((N_ + 1) * 4);
  int*   ptr_att = (int*)alloc((N_ + 1) * 4);
  int*   gcn_src = (int*)alloc(EN_ * 4);
  float* gcn_w   = (float*)alloc(EN_ * 4);
  int*   att_src = (int*)alloc(E_ * 4);
  float* AB      = (float*)alloc((size_t)12 * 320 * 16 * 4);  // 245 KB
  float* cd      = (float*)alloc(32 * 4);
  float* Wkt     = (float*)alloc((size_t)64 * QK_ * 4);       // 64 KB
  float* vc      = (float*)alloc(260 * 4);
  float* zero256 = (float*)alloc(256 * 4);
  float* bb      = (float*)alloc((size_t)ROWS_ * 4 * 4);      // 1 MB
  float* ag = (float*)alloc((size_t)ROWS_ * H_ * 4);       // 16 MB (agg scratch)
  float* h0 = (float*)alloc((size_t)ROWS_ * H_ * 4);       // 16 MB
  float* h1 = (float*)alloc((size_t)ROWS_ * H_ * 4);       // 16 MB (xt)
  float* ktb = (float*)alloc((size_t)HROWS_ * QK_ * 4);    // 32 MB (per half)
  float* partial = (float*)alloc((size_t)ROWS_ * 12 * 4);  // 3 MB
  (void)ws_size; (void)in_sizes; (void)n_in; (void)out_size;

  k_deg<<<1, 512, 0, stream>>>(ei, ptr_gcn, ptr_att, dinv);
  k_fill<<<(EN_ + 255) / 256, 256, 0, stream>>>(ei, ptr_gcn, ptr_att, dinv,
                                                gcn_src, gcn_w, att_src);
  k_abcd<<<306, 256, 0, stream>>>(Wv, Ws, Wl, bl, bs, bv, Wq, bq, Wk, bk,
                                  AB, cd, Wkt, vc, zero256);

  // GCN layers: agg (SpMM) + tiled GEMM, ping-pong x -> h0 -> h1 -> h0 -> h1
  dim3 agrid((N_ + 3) / 4, BS_);
  int mt = (ROWS_ + 127) / 128;     // 488
  k_agg<CIN_><<<agrid, 256, 0, stream>>>(x, ptr_gcn, gcn_src, gcn_w, ag);
  k_gemm<CIN_, true><<<dim3(mt, 1), 256, 0, stream>>>(ag, ROWS_, Wg[0], bg[0], h0,
                                                      Wg[0], bg[0], h0, 64, 64, 1);
  k_agg<H_><<<agrid, 256, 0, stream>>>(h0, ptr_gcn, gcn_src, gcn_w, ag);
  k_gemm<H_, true><<<dim3(mt, 1), 256, 0, stream>>>(ag, ROWS_, Wg[1], bg[1], h1,
                                                    Wg[1], bg[1], h1, 64, 64, 1);
  k_agg<H_><<<agrid, 256, 0, stream>>>(h1, ptr_gcn, gcn_src, gcn_w, ag);
  k_gemm<H_, true><<<dim3(mt, 1), 256, 0, stream>>>(ag, ROWS_, Wg[2], bg[2], h0,
                                                    Wg[2], bg[2], h0, 64, 64, 1);
  k_agg<H_><<<agrid, 256, 0, stream>>>(h0, ptr_gcn, gcn_src, gcn_w, ag);
  k_gemm<H_, true><<<dim3(mt, 1), 256, 0, stream>>>(ag, ROWS_, Wg[3], bg[3], h1,
                                                    Wg[3], bg[3], h1, 64, 64, 1);

  // beta over all rows (depends only on xt = h1)
  k_beta<<<ROWS_ / 64, 256, 0, stream>>>(h1, vc, bb);

  int mth = (HROWS_ + 127) / 128;   // 244
  for (int half = 0; half < 2; half++) {
    const float* xh = h1 + (size_t)half * HROWS_ * 64;
    // kt = xt @ Wkt  (4 head-slices)
    k_gemm<H_, false><<<dim3(mth, 4), 256, 0, stream>>>(xh, HROWS_, Wkt, zero256, ktb,
                                                        Wkt, zero256, ktb, QK_, QK_, 4);
    k_attnfin<<<dim3((N_ + 3) / 4, HBS_), 256, 0, stream>>>(ktb, h1, bb, AB,
                                                            ptr_att, att_src, half,
                                                            partial);
  }
  k_red<<<(B_ * N_ * 12 + 255) / 256, 256, 0, stream>>>(partial, cd, ptr_att, y);
}

// Round 14
// 423.415 us; speedup vs baseline: 1.0278x; 1.0278x over previous
//
#include <hip/hip_runtime.h>

#define B_ 16
#define S_ 12
#define N_ 325
#define E_ 2600
#define CIN_ 32
#define H_ 64
#define HEADS_ 4
#define COUT_ 12
#define BS_ (B_*S_)          // 192
#define ROWS_ (BS_*N_)       // 62400
#define EN_ (E_+N_)          // 2925
#define QK_ 256
#define HB_ (B_/2)           // 8 b per half
#define HBS_ (BS_/2)         // 96
#define HROWS_ (ROWS_/2)     // 31200
#define NCH_ 82              // ceil(N/4) n-chunks per bs

__device__ __forceinline__ int swz8(int bid, int cpx) {
  return (bid & 7) * cpx + (bid >> 3);   // grid must be multiple of 8
}

// ---------------- degree / norm / CSR pointers ----------------
__global__ void k_deg(const int* __restrict__ ei, int* __restrict__ ptr_gcn,
                      int* __restrict__ ptr_att, float* __restrict__ dinv) {
  __shared__ int cnt[N_];
  for (int i = threadIdx.x; i < N_; i += blockDim.x) cnt[i] = 0;
  __syncthreads();
  for (int e = threadIdx.x; e < E_; e += blockDim.x)
    atomicAdd(&cnt[ei[E_ + e]], 1);   // col = target
  __syncthreads();
  for (int n = threadIdx.x; n < N_; n += blockDim.x)
    dinv[n] = rsqrtf((float)(cnt[n] + 1));
  if (threadIdx.x == 0) {
    int a = 0, g = 0;
    for (int n = 0; n < N_; n++) {
      ptr_att[n] = a; ptr_gcn[n] = g;
      a += cnt[n]; g += cnt[n] + 1;   // gcn bucket has +1 self-loop slot
    }
    ptr_att[N_] = a; ptr_gcn[N_] = g;
  }
}

// ---------------- deterministic CSR fill (stable rank) ----------------
__global__ void k_fill(const int* __restrict__ ei, const int* __restrict__ ptr_gcn,
                       const int* __restrict__ ptr_att, const float* __restrict__ dinv,
                       int* __restrict__ gcn_src, float* __restrict__ gcn_w,
                       int* __restrict__ att_src) {
  __shared__ int cols[E_];
  for (int i = threadIdx.x; i < E_; i += blockDim.x) cols[i] = ei[E_ + i];
  __syncthreads();
  int e = blockIdx.x * blockDim.x + threadIdx.x;
  if (e >= EN_) return;
  int t = (e < E_) ? cols[e] : (e - E_);
  int s = (e < E_) ? ei[e]   : (e - E_);
  int lim = (e < E_) ? e : E_;
  int rank = 0;
  for (int j = 0; j < lim; j++) rank += (cols[j] == t);
  int pos = ptr_gcn[t] + rank;
  gcn_src[pos] = s;
  gcn_w[pos] = dinv[s] * dinv[t];
  if (e < E_) att_src[ptr_att[t] + rank] = s;
}

// ---------------- setup: AB, cd, Wkt (=G_h^T packed), vvec, c4, zero256 ----------------
// blocks 0..239: AB ; 240: cd ; 241..304: Wkt ; 305: vvec + c4 + zero256
__global__ void k_abcd(const float* __restrict__ Wv, const float* __restrict__ Wsm,
                       const float* __restrict__ Wl, const float* __restrict__ bl,
                       const float* __restrict__ bsv, const float* __restrict__ bvv,
                       const float* __restrict__ Wq, const float* __restrict__ bq,
                       const float* __restrict__ Wk, const float* __restrict__ bk,
                       float* __restrict__ AB, float* __restrict__ cd,
                       float* __restrict__ Wkt, float* __restrict__ vc,
                       float* __restrict__ zero256) {
  int t = threadIdx.x;
  if (blockIdx.x < 240) {
    int s = blockIdx.x / 20, dblk = blockIdx.x % 20;
    int dl = t >> 4, co = t & 15;
    int d = dblk * 16 + dl;             // 0..319
    float acc = 0.f;
    if (co < 12) {
      if (d < 256) {
        int h = d >> 6, dd = d & 63;
        for (int j = 0; j < 64; j++)
          acc += Wv[dd * 256 + h * 64 + j] * Wl[(size_t)(s * 256 + h * 64 + j) * 12 + co];
      } else {
        int d0 = d - 256;
        for (int J = 0; J < 256; J++)
          acc += Wsm[d0 * 256 + J] * Wl[(size_t)(s * 256 + J) * 12 + co];
      }
    }
    AB[((size_t)s * 320 + d) * 16 + co] = acc;
  } else if (blockIdx.x == 240) {
    __shared__ float red[2][16][17];
    int co = t & 15, chunk = t >> 4;
    float c = 0.f, dv = 0.f;
    if (co < 12) {
      for (int J = chunk * 192; J < chunk * 192 + 192; J++) {
        float wl = Wl[(size_t)J * 12 + co];
        c  += bsv[J & 255] * wl;
        dv += bvv[J & 255] * wl;
      }
    }
    red[0][chunk][co] = c;
    red[1][chunk][co] = dv;
    __syncthreads();
    if (t < 16) {
      float s0 = 0.f;
      for (int ch = 0; ch < 16; ch++) s0 += red[0][ch][t];
      cd[t] = s0 + ((t < 12) ? bl[t] : 0.f);
    } else if (t < 32) {
      int co2 = t - 16;
      float s1 = 0.f;
      for (int ch = 0; ch < 16; ch++) s1 += red[1][ch][co2];
      cd[16 + co2] = s1;
    }
  } else if (blockIdx.x < 305) {
    // Wkt[e][h*64+d] = G_h[d][e] = sum_i Wq[d][h*64+i] * Wk[e][h*64+i]
    int idx = (blockIdx.x - 241) * 256 + t;    // 0..16383
    int e = idx >> 8, col = idx & 255;
    int h = col >> 6, d = col & 63;
    float acc = 0.f;
    const float* wqr = Wq + (size_t)d * QK_ + h * 64;
    const float* wkr = Wk + (size_t)e * QK_ + h * 64;
#pragma unroll 8
    for (int i = 0; i < 64; i++) acc += wqr[i] * wkr[i];
    Wkt[(size_t)e * QK_ + col] = acc;
  } else {
    // vvec[h*64+e] = sum_i Wk[e][h*64+i] * bq[h*64+i] ; vc[256..259] = c_h ; zero256
    int h = t >> 6, e = t & 63;
    float acc = 0.f;
    const float* wkr = Wk + (size_t)e * QK_ + h * 64;
    const float* bqr = bq + h * 64;
#pragma unroll 8
    for (int i = 0; i < 64; i++) acc += wkr[i] * bqr[i];
    vc[t] = acc;
    if (t < 4) {
      float cc = 0.f;
      for (int i = 0; i < 64; i++) cc += bq[t * 64 + i] * bk[t * 64 + i];
      vc[256 + t] = cc;
    }
    zero256[t] = 0.f;
  }
}

// ---------------- GCN aggregation (SpMM), 4-way unrolled independent gathers ----------------
template<int K>
__global__ __launch_bounds__(256) void k_agg(const float* __restrict__ hin,
    const int* __restrict__ ptr, const int* __restrict__ src,
    const float* __restrict__ wgt, float* __restrict__ ag) {
  int wid = threadIdx.x >> 6, lane = threadIdx.x & 63;
  int n = blockIdx.x * 4 + wid;
  int bs = blockIdx.y;
  if (n >= N_ || (K != 64 && lane >= K)) return;
  int p0 = ptr[n], p1 = ptr[n + 1];
  const float* base = hin + (size_t)bs * N_ * K;
  float a0 = 0.f, a1 = 0.f, a2 = 0.f, a3 = 0.f;
  int e = p0;
  for (; e + 4 <= p1; e += 4) {
    a0 += wgt[e]     * base[src[e]     * K + lane];
    a1 += wgt[e + 1] * base[src[e + 1] * K + lane];
    a2 += wgt[e + 2] * base[src[e + 2] * K + lane];
    a3 += wgt[e + 3] * base[src[e + 3] * K + lane];
  }
  for (; e < p1; ++e) a0 += wgt[e] * base[src[e] * K + lane];
  ag[((size_t)bs * N_ + n) * K + lane] = (a0 + a1) + (a2 + a3);
}

// ---------------- tiled GEMM: C[M x 64-slice] = A[M x K] @ W[:,c0:c0+64] + bias (opt relu) ----
template<int K, bool RELU>
__global__ __launch_bounds__(256) void k_gemm(
    const float* __restrict__ A, int M,
    const float* __restrict__ W0, const float* __restrict__ b0, float* __restrict__ C0,
    const float* __restrict__ W1, const float* __restrict__ b1, float* __restrict__ C1,
    int wstride, int cstride, int nct) {
  __shared__ float Ast[K][136];
  __shared__ float Wsh[K][68];
  int t = threadIdx.x;
  int ct = blockIdx.y;
  const float* W   = (ct < nct) ? W0 : W1;
  const float* bia = (ct < nct) ? b0 : b1;
  float* C         = (ct < nct) ? C0 : C1;
  int c0 = (ct & (nct - 1)) * 64;          // nct is 1 or 4 (power of 2)
  for (int i = t; i < K * 64; i += 256)
    Wsh[i >> 6][i & 63] = W[(size_t)(i >> 6) * wstride + c0 + (i & 63)];
  int r0 = blockIdx.x * 128;
  constexpr int KQ = K / 4;
#pragma unroll
  for (int it = 0; it < KQ / 2; ++it) {    // 128*KQ/256 iters
    int idx = it * 256 + t;
    int dq = idx >> 7, rl = idx & 127;
    int ar = min(r0 + rl, M - 1);
    float4 v = *(const float4*)(A + (size_t)ar * K + dq * 4);
    Ast[dq * 4 + 0][rl] = v.x; Ast[dq * 4 + 1][rl] = v.y;
    Ast[dq * 4 + 2][rl] = v.z; Ast[dq * 4 + 3][rl] = v.w;
  }
  __syncthreads();
  int tr = t >> 4, tc = t & 15;            // rows tr*8..+7, cols tc*4..+3
  float acc[8][4];
#pragma unroll
  for (int i = 0; i < 8; i++)
#pragma unroll
    for (int j = 0; j < 4; j++) acc[i][j] = 0.f;
#pragma unroll 8
  for (int k = 0; k < K; k++) {
    float4 w4 = *(const float4*)&Wsh[k][tc * 4];
    float4 a0 = *(const float4*)&Ast[k][tr * 8];
    float4 a1 = *(const float4*)&Ast[k][tr * 8 + 4];
    const float av[8] = {a0.x, a0.y, a0.z, a0.w, a1.x, a1.y, a1.z, a1.w};
#pragma unroll
    for (int i = 0; i < 8; i++) {
      acc[i][0] += av[i] * w4.x; acc[i][1] += av[i] * w4.y;
      acc[i][2] += av[i] * w4.z; acc[i][3] += av[i] * w4.w;
    }
  }
  float4 b4 = *(const float4*)&bia[c0 + tc * 4];
#pragma unroll
  for (int i = 0; i < 8; i++) {
    int row = r0 + tr * 8 + i;
    if (row < M) {
      float4 o = make_float4(acc[i][0] + b4.x, acc[i][1] + b4.y,
                             acc[i][2] + b4.z, acc[i][3] + b4.w);
      if (RELU) {
        o.x = fmaxf(o.x, 0.f); o.y = fmaxf(o.y, 0.f);
        o.z = fmaxf(o.z, 0.f); o.w = fmaxf(o.w, 0.f);
      }
      *(float4*)(C + (size_t)row * cstride + c0 + tc * 4) = o;
    }
  }
}

// ---------------- beta: bb[row][h] = xt_row . vvec_h + c_h ----------------
__global__ __launch_bounds__(256) void k_beta(const float* __restrict__ xt,
    const float* __restrict__ vc, float* __restrict__ bb) {
  __shared__ float vs[260];
  int t = threadIdx.x;
  vs[t] = vc[t];
  if (t < 4) vs[256 + t] = vc[256 + t];
  __syncthreads();
  int row = blockIdx.x * 64 + (t >> 2), h = t & 3;
  const float4* xr = (const float4*)(xt + (size_t)row * 64);
  const float4* vr = (const float4*)&vs[h * 64];
  float d0 = 0.f, d1 = 0.f;
#pragma unroll
  for (int j = 0; j < 16; j += 2) {
    float4 xa = xr[j], va = vr[j];
    float4 xb2 = xr[j + 1], vb = vr[j + 1];
    d0 += xa.x * va.x + xa.y * va.y + xa.z * va.z + xa.w * va.w;
    d1 += xb2.x * vb.x + xb2.y * vb.y + xb2.z * vb.z + xb2.w * vb.w;
  }
  bb[(size_t)row * 4 + h] = d0 + d1 + vs[256 + h];
}

// ---------------- fused attention + final-slice GEMM, XCD-partitioned ----------------
// 1D grid 7872 = 8 XCDs x (12 bs x 82 n-chunks). Each XCD owns 12 bs slices:
// kt(332KB)+xt(83KB) x12 ~ 5MB ~ one XCD L2 -> consecutive blocks reuse the slice.
__global__ __launch_bounds__(256) void k_attnfin(const float* __restrict__ kt,
    const float* __restrict__ xt, const float* __restrict__ bb,
    const float* __restrict__ AB, const int* __restrict__ ptr,
    const int* __restrict__ src, int half, float* __restrict__ partial) {
  __shared__ float xs[4][68];
  __shared__ float ABs[320][17];           // pad 17: fin reads land 2 lanes/bank
  int t = threadIdx.x, wid = t >> 6, lane = t & 63;
  int bid = blockIdx.x;                    // 7872 = 8 * 984, 984 = 12 * 82
  int xcd = bid & 7, sub = bid >> 3;
  int bsl = xcd * 12 + sub / NCH_;         // 0..95, contiguous per XCD
  int nchunk = sub % NCH_;
  int s = bsl % 12;
  const float* ABg = AB + (size_t)s * 320 * 16;
  for (int i = t; i < 1280; i += 256) {    // stage AB slice (20 KB)
    float4 v = ((const float4*)ABg)[i];
    int d = i >> 2, q = (i & 3) * 4;
    ABs[d][q] = v.x; ABs[d][q + 1] = v.y; ABs[d][q + 2] = v.z; ABs[d][q + 3] = v.w;
  }
  int n = nchunk * 4 + wid;
  const float* xb = xt + ((size_t)half * HBS_ + bsl) * N_ * 64;
  if (n < N_) xs[wid][lane] = xb[(size_t)n * 64 + lane];
  __syncthreads();
  if (n >= N_) return;                     // wave-uniform, after the only barrier
  int p0 = ptr[n], p1 = ptr[n + 1];
  int h = lane & 3, el = lane >> 2;
  const float* kb = kt + (size_t)bsl * N_ * QK_;
  const float* bbb = bb + ((size_t)half * HROWS_ + (size_t)bsl * N_) * 4;
  const float4* x4 = reinterpret_cast<const float4*>(&xs[wid][0]);
  float m = -INFINITY, den = 0.f;
  float zacc[4] = {0.f, 0.f, 0.f, 0.f};
  for (int base = p0; base < p1; base += 16) {
    int slot = base + el;
    bool valid = slot < p1;
    int sidx = valid ? src[slot] : 0;
    float logit = -INFINITY;
    if (valid) {
      const float4* k4 = reinterpret_cast<const float4*>(kb + (size_t)sidx * QK_ + h * 64);
      float d0 = 0.f, d1 = 0.f;
#pragma unroll
      for (int j = 0; j < 16; j += 2) {
        float4 ka = k4[j], kb2 = k4[j + 1];
        float4 xa = x4[j], xb2 = x4[j + 1];
        d0 += xa.x * ka.x + xa.y * ka.y + xa.z * ka.z + xa.w * ka.w;
        d1 += xb2.x * kb2.x + xb2.y * kb2.y + xb2.z * kb2.z + xb2.w * kb2.w;
      }
      logit = (d0 + d1 + bbb[sidx * 4 + h]) * 0.125f;   // 1/sqrt(64)
    }
    float cm = logit;
#pragma unroll
    for (int o = 4; o < 64; o <<= 1) cm = fmaxf(cm, __shfl_xor(cm, o));
    float mnew = fmaxf(m, cm);
    float scale = __expf(m - mnew);        // first chunk: exp(-inf)=0
    float w = valid ? __expf(logit - mnew) : 0.f;
    float wsum = w;
#pragma unroll
    for (int o = 4; o < 64; o <<= 1) wsum += __shfl_xor(wsum, o);
    den = den * scale + wsum;
#pragma unroll
    for (int h2 = 0; h2 < 4; h2++) zacc[h2] *= __shfl(scale, h2);
    int cnt = min(16, p1 - base);
    for (int e2 = 0; e2 < cnt; e2++) {
      int s_e = __shfl(sidx, e2 * 4);
      float xv = xb[(size_t)s_e * 64 + lane];
#pragma unroll
      for (int h2 = 0; h2 < 4; h2++)
        zacc[h2] += __shfl(w, e2 * 4 + h2) * xv;
    }
    m = mnew;
  }
  bool ok = p1 > p0;
  float zn[4];
#pragma unroll
  for (int h2 = 0; h2 < 4; h2++) {
    float dh = __shfl(den, h2);
    zn[h2] = ok ? zacc[h2] / (dh + 1e-16f) : 0.f;
  }
  // fused final-slice: per-lane contributions, butterfly reduce, lane0 writes 12
  float xv = xs[wid][lane];
  float pl[12];
#pragma unroll
  for (int co = 0; co < 12; co++)
    pl[co] = zn[0] * ABs[lane][co] + zn[1] * ABs[64 + lane][co]
           + zn[2] * ABs[128 + lane][co] + zn[3] * ABs[192 + lane][co]
           + xv * ABs[256 + lane][co];
#pragma unroll
  for (int o = 1; o < 64; o <<= 1) {
#pragma unroll
    for (int co = 0; co < 12; co++) pl[co] += __shfl_xor(pl[co], o);
  }
  if (lane == 0) {
    float* pr = partial + ((size_t)half * HROWS_ + (size_t)bsl * N_ + n) * 12;
    *(float4*)(pr)     = make_float4(pl[0], pl[1], pl[2], pl[3]);
    *(float4*)(pr + 4) = make_float4(pl[4], pl[5], pl[6], pl[7]);
    *(float4*)(pr + 8) = make_float4(pl[8], pl[9], pl[10], pl[11]);
  }
}

// ---------------- y = sum_s partial + cvec + 1{deg>0} dvec ----------------
__global__ void k_red(const float* __restrict__ partial, const float* __restrict__ cd,
                      const int* __restrict__ ptr, float* __restrict__ y) {
  int tg = blockIdx.x * 256 + threadIdx.x;
  if (tg >= B_ * N_ * 12) return;
  int bn = tg / 12, co = tg % 12;
  int b = bn / N_, n = bn % N_;
  float acc = cd[co];
  if (ptr[n + 1] > ptr[n]) acc += cd[16 + co];
  for (int s = 0; s < 12; s++)
    acc += partial[(((size_t)(b * 12 + s)) * N_ + n) * 12 + co];
  y[(size_t)bn * 12 + co] = acc;
}

extern "C" void kernel_launch(void* const* d_in, const int* in_sizes, int n_in,
                              void* d_out, int out_size, void* d_ws, size_t ws_size,
                              hipStream_t stream) {
  const float* x   = (const float*)d_in[0];
  const int*   ei  = (const int*)d_in[1];
  const float* Wg[4] = {(const float*)d_in[2], (const float*)d_in[4],
                        (const float*)d_in[6], (const float*)d_in[8]};
  const float* bg[4] = {(const float*)d_in[3], (const float*)d_in[5],
                        (const float*)d_in[7], (const float*)d_in[9]};
  const float* Wq = (const float*)d_in[10]; const float* bq = (const float*)d_in[11];
  const float* Wk = (const float*)d_in[12]; const float* bk = (const float*)d_in[13];
  const float* Wv = (const float*)d_in[14]; const float* bv = (const float*)d_in[15];
  const float* Ws = (const float*)d_in[16]; const float* bs = (const float*)d_in[17];
  const float* Wl = (const float*)d_in[18]; const float* bl = (const float*)d_in[19];
  float* y = (float*)d_out;

  char* p = (char*)d_ws;
  auto alloc = [&](size_t bytes) {
    char* r = p;
    p += (bytes + 255) & ~(size_t)255;
    return r;
  };
  float* dinv    = (float*)alloc(N_ * 4);
  int*   ptr_gcn = (int*)alloc((N_ + 1) * 4);
  int*   ptr_att = (int*)alloc((N_ + 1) * 4);
  int*   gcn_src = (int*)alloc(EN_ * 4);
  float* gcn_w   = (float*)alloc(EN_ * 4);
  int*   att_src = (int*)alloc(E_ * 4);
  float* AB      = (float*)alloc((size_t)12 * 320 * 16 * 4);  // 245 KB
  float* cd      = (float*)alloc(32 * 4);
  float* Wkt     = (float*)alloc((size_t)64 * QK_ * 4);       // 64 KB
  float* vc      = (float*)alloc(260 * 4);
  float* zero256 = (float*)alloc(256 * 4);
  float* bb      = (float*)alloc((size_t)ROWS_ * 4 * 4);      // 1 MB
  float* ag = (float*)alloc((size_t)ROWS_ * H_ * 4);       // 16 MB (agg scratch)
  float* h0 = (float*)alloc((size_t)ROWS_ * H_ * 4);       // 16 MB
  float* h1 = (float*)alloc((size_t)ROWS_ * H_ * 4);       // 16 MB (xt)
  float* ktb = (float*)alloc((size_t)HROWS_ * QK_ * 4);    // 32 MB (per half)
  float* partial = (float*)alloc((size_t)ROWS_ * 12 * 4);  // 3 MB
  (void)ws_size; (void)in_sizes; (void)n_in; (void)out_size;

  k_deg<<<1, 512, 0, stream>>>(ei, ptr_gcn, ptr_att, dinv);
  k_fill<<<(EN_ + 255) / 256, 256, 0, stream>>>(ei, ptr_gcn, ptr_att, dinv,
                                                gcn_src, gcn_w, att_src);
  k_abcd<<<306, 256, 0, stream>>>(Wv, Ws, Wl, bl, bs, bv, Wq, bq, Wk, bk,
                                  AB, cd, Wkt, vc, zero256);

  // GCN layers: agg (SpMM) + tiled GEMM, ping-pong x -> h0 -> h1 -> h0 -> h1
  dim3 agrid((N_ + 3) / 4, BS_);
  int mt = (ROWS_ + 127) / 128;     // 488
  k_agg<CIN_><<<agrid, 256, 0, stream>>>(x, ptr_gcn, gcn_src, gcn_w, ag);
  k_gemm<CIN_, true><<<dim3(mt, 1), 256, 0, stream>>>(ag, ROWS_, Wg[0], bg[0], h0,
                                                      Wg[0], bg[0], h0, 64, 64, 1);
  k_agg<H_><<<agrid, 256, 0, stream>>>(h0, ptr_gcn, gcn_src, gcn_w, ag);
  k_gemm<H_, true><<<dim3(mt, 1), 256, 0, stream>>>(ag, ROWS_, Wg[1], bg[1], h1,
                                                    Wg[1], bg[1], h1, 64, 64, 1);
  k_agg<H_><<<agrid, 256, 0, stream>>>(h1, ptr_gcn, gcn_src, gcn_w, ag);
  k_gemm<H_, true><<<dim3(mt, 1), 256, 0, stream>>>(ag, ROWS_, Wg[2], bg[2], h0,
                                                    Wg[2], bg[2], h0, 64, 64, 1);
  k_agg<H_><<<agrid, 256, 0, stream>>>(h0, ptr_gcn, gcn_src, gcn_w, ag);
  k_gemm<H_, true><<<dim3(mt, 1), 256, 0, stream>>>(ag, ROWS_, Wg[3], bg[3], h1,
                                                    Wg[3], bg[3], h1, 64, 64, 1);

  // beta over all rows (depends only on xt = h1)
  k_beta<<<ROWS_ / 64, 256, 0, stream>>>(h1, vc, bb);

  int mth = (HROWS_ + 127) / 128;   // 244
  for (int half = 0; half < 2; half++) {
    const float* xh = h1 + (size_t)half * HROWS_ * 64;
    // kt = xt @ Wkt  (4 head-slices)
    k_gemm<H_, false><<<dim3(mth, 4), 256, 0, stream>>>(xh, HROWS_, Wkt, zero256, ktb,
                                                        Wkt, zero256, ktb, QK_, QK_, 4);
    k_attnfin<<<8 * 12 * NCH_, 256, 0, stream>>>(ktb, h1, bb, AB,
                                                 ptr_att, att_src, half, partial);
  }
  k_red<<<(B_ * N_ * 12 + 255) / 256, 256, 0, stream>>>(partial, cd, ptr_att, y);
}